// Round 12
// baseline (81.742 us; speedup 1.0000x reference)
//
#include <hip/hip_runtime.h>

typedef __attribute__((ext_vector_type(2))) float f32x2;

#define NS 1024      // N samples
#define MM 64        // M patches
#define CC 4         // C compartments
#define NSTEPS 100
#define CLIPMAX 1e10f

// Broadcast lane k's value to all lanes via v_readlane.
__device__ __forceinline__ float rdlane(float v, int k) {
    return __uint_as_float(__builtin_amdgcn_readlane(__float_as_uint(v), k));
}
// Force a (wave-uniform) value into an SGPR.
__device__ __forceinline__ float sfirst(float v) {
    return __uint_as_float(__builtin_amdgcn_readfirstlane(__float_as_uint(v)));
}

// One wave per sample, barrier-free, register-resident state (r10), PLUS the
// r11 fix: the per-step trajectory store no longer serializes the loop.
// r2-r10 invariant (~80 us across totally different VALU bodies) diagnosed as
// a store-data VGPR reuse hazard: reusing the payload quad each step forces
// s_waitcnt vmcnt(0) = wait for the previous store to COMPLETE (~600-900
// cyc/step). Fix: unroll x4 with 4 rotating payload quads (held live together
// via scalar asm keep-alives) + 4 loop-carried address regs, so each
// redefinition has 3 younger stores outstanding -> vmcnt(3), never blocks.
extern "C" __global__
__attribute__((amdgpu_flat_work_group_size(64, 64), amdgpu_waves_per_eu(1, 1)))
void metapop_kernel(
    const float* __restrict__ R,     // (NS, MM, MM)
    const float* __restrict__ T,     // (NS, CC, CC)
    const float* __restrict__ rho0,  // (NS, MM, CC)
    const float* __restrict__ beta,  // (NS,)
    float* __restrict__ out)         // (NSTEPS, NS, MM, CC)
{
    const int n    = blockIdx.x;
    const int lane = threadIdx.x;    // 0..63

    const float* Rn = R + (size_t)n * (MM * MM);

    // ---- Rrow pairs: Rrow[k2] = (R[n,lane,2k2], R[n,lane,2k2+1]) ----
    f32x2 Rrow[32];
    {
        const float4* p4 = (const float4*)(Rn + lane * MM);
        #pragma unroll
        for (int q = 0; q < 16; ++q) {
            float4 v = p4[q];
            Rrow[2*q]   = (f32x2){v.x, v.y};
            Rrow[2*q+1] = (f32x2){v.z, v.w};
        }
    }

    // ---- ntot[lane] = sum_i R[n,i,lane] ----
    float nt = 0.f;
    #pragma unroll
    for (int i = 0; i < MM; ++i) nt += Rn[i * MM + lane];
    const float binv = beta[n] / nt;   // lane j holds beta/ntot[j]

    // ---- Gcol pairs via the transpose bijection ----
    // Rt[n,i,j] = R[(i&15)*64+j, (n&15)*4+(i>>4), n>>4]
    f32x2 Gcol[32];
    {
        const int q     = n >> 4;
        const int a     = ((n & 15) << 2) + (lane >> 4);
        const int sbase = (lane & 15) << 6;
        #pragma unroll
        for (int j2 = 0; j2 < 32; ++j2) {
            const int j0 = 2 * j2, j1 = 2 * j2 + 1;
            float v0 = R[(size_t)(sbase + j0) * (MM * MM) + a * MM + q];
            float v1 = R[(size_t)(sbase + j1) * (MM * MM) + a * MM + q];
            Gcol[j2] = (f32x2){v0 * rdlane(binv, j0), v1 * rdlane(binv, j1)};
        }
    }

    // ---- PIN state into VGPRs (with waves_per_eu(1,1); r4/r10 proof) ----
    #pragma unroll
    for (int q = 0; q < 32; ++q) asm volatile("" : "+v"(Rrow[q]));
    #pragma unroll
    for (int q = 0; q < 32; ++q) asm volatile("" : "+v"(Gcol[q]));

    // ---- T[n]: wave-uniform -> SGPRs ----
    float tt[CC][CC];
    {
        const float* Tn = T + n * (CC * CC);
        #pragma unroll
        for (int k = 0; k < CC; ++k)
            #pragma unroll
            for (int l = 0; l < CC; ++l)
                tt[k][l] = sfirst(Tn[k * CC + l]);
    }

    // ---- rho0 ----
    float rh[CC];
    {
        float4 v = *(const float4*)(rho0 + (size_t)n * (MM * CC) + lane * CC);
        rh[0] = v.x; rh[1] = v.y; rh[2] = v.z; rh[3] = v.w;
    }

    // one full state update (rh -> rh')
    auto step_update = [&]() {
        // phase A (lane = i): p = 1 - prod_j (1 - rho1*Gcol[j]); packed, 4 chains
        const float r1  = rh[1];
        const f32x2 r1v = {r1, r1};
        const f32x2 one = {1.f, 1.f};
        f32x2 pa = one, pb = one, pc = one, pd = one;
        #pragma unroll
        for (int j2 = 0; j2 < 8; ++j2) {
            pa *= one - r1v * Gcol[j2];
            pb *= one - r1v * Gcol[j2 + 8];
            pc *= one - r1v * Gcol[j2 + 16];
            pd *= one - r1v * Gcol[j2 + 24];
        }
        const f32x2 pq = (pa * pb) * (pc * pd);
        const float p  = 1.f - pq.x * pq.y;

        // phase B (lane = j): s = sum_k Rrow[k]*p[k]; readlane broadcast, 4 chains
        float s0 = 0.f, s1 = 0.f, s2 = 0.f, s3 = 0.f;
        #pragma unroll
        for (int k2 = 0; k2 < 8; ++k2) {
            const f32x2 rA = Rrow[k2],      rB = Rrow[k2 + 8];
            const f32x2 rC = Rrow[k2 + 16], rD = Rrow[k2 + 24];
            s0 += rA.x * rdlane(p, 2*k2)      + rA.y * rdlane(p, 2*k2 + 1);
            s1 += rB.x * rdlane(p, 2*k2 + 16) + rB.y * rdlane(p, 2*k2 + 17);
            s2 += rC.x * rdlane(p, 2*k2 + 32) + rC.y * rdlane(p, 2*k2 + 33);
            s3 += rD.x * rdlane(p, 2*k2 + 48) + rD.y * rdlane(p, 2*k2 + 49);
        }
        const float ssum = (s0 + s1) + (s2 + s3);
        const float sr   = (rh[0] + rh[1]) + (rh[2] + rh[3]);
        const float ninf = (1.f - sr) * ssum;

        // phase C: rho_new[l] = sum_k rho[k]*T[k,l] (+ninf at l=0), clipped
        float nr[CC];
        #pragma unroll
        for (int l = 0; l < CC; ++l) {
            float v = rh[0] * tt[0][l] + rh[1] * tt[1][l]
                    + rh[2] * tt[2][l] + rh[3] * tt[3][l];
            if (l == 0) v += ninf;
            nr[l] = fminf(fmaxf(v, 0.f), CLIPMAX);
        }
        #pragma unroll
        for (int l = 0; l < CC; ++l) rh[l] = nr[l];
    };

    // 4 persistent store addresses, advanced by 4*stride per unrolled iter
    // (loop-carried -> live in distinct registers without asm)
    const size_t stride = (size_t)NS * MM * CC;
    float* oa0 = out + (size_t)n * (MM * CC) + lane * CC;
    float* oa1 = oa0 + stride;
    float* oa2 = oa1 + stride;
    float* oa3 = oa2 + stride;

    for (int it = 0; it < NSTEPS / 4; ++it) {
        float4 pay0 = make_float4(rh[0], rh[1], rh[2], rh[3]);
        *(float4*)oa0 = pay0;
        step_update();

        float4 pay1 = make_float4(rh[0], rh[1], rh[2], rh[3]);
        *(float4*)oa1 = pay1;
        step_update();

        float4 pay2 = make_float4(rh[0], rh[1], rh[2], rh[3]);
        *(float4*)oa2 = pay2;
        step_update();

        float4 pay3 = make_float4(rh[0], rh[1], rh[2], rh[3]);
        *(float4*)oa3 = pay3;
        step_update();

        // keep all 4 payload quads simultaneously live (scalar constraints:
        // vector aggregates are not valid "v" asm inputs on this compiler) ->
        // distinct payload registers -> each redefinition has 3 younger
        // stores outstanding (vmcnt(3), non-blocking) instead of vmcnt(0).
        asm volatile("" :: "v"(pay0.x), "v"(pay0.y), "v"(pay0.z), "v"(pay0.w),
                           "v"(pay1.x), "v"(pay1.y), "v"(pay1.z), "v"(pay1.w));
        asm volatile("" :: "v"(pay2.x), "v"(pay2.y), "v"(pay2.z), "v"(pay2.w),
                           "v"(pay3.x), "v"(pay3.y), "v"(pay3.z), "v"(pay3.w));

        oa0 += 4 * stride; oa1 += 4 * stride;
        oa2 += 4 * stride; oa3 += 4 * stride;
    }
}

extern "C" void kernel_launch(void* const* d_in, const int* in_sizes, int n_in,
                              void* d_out, int out_size, void* d_ws, size_t ws_size,
                              hipStream_t stream) {
    const float* R    = (const float*)d_in[0];
    const float* T    = (const float*)d_in[1];
    const float* rho0 = (const float*)d_in[2];
    const float* beta = (const float*)d_in[3];
    float* out = (float*)d_out;
    hipLaunchKernelGGL(metapop_kernel, dim3(NS), dim3(64), 0, stream,
                       R, T, rho0, beta, out);
}